// Round 1
// baseline (23354.123 us; speedup 1.0000x reference)
//
#include <hip/hip_runtime.h>

#define NN 50000
#define EE 800000
#define TT 12
#define HH 128
#define NHEADS 4
#define CH 32
#define LLAYERS 3
#define OO 12
#define G3H 384

__device__ __forceinline__ float sigmoidf_(float x) { return 1.f / (1.f + expf(-x)); }

__device__ __forceinline__ void atomicMaxFloat(float* addr, float val) {
    val += 0.0f;  // normalize -0.0 -> +0.0
    if (val >= 0.f) atomicMax((int*)addr, __float_as_int(val));
    else            atomicMin((unsigned int*)addr, __float_as_uint(val));
}

// ---------------------------------------------------------------------------
// Generic fp32 GEMM: C[M,Ngc] = A[M,128] * B[Ngc,128]^T + bias, optional relu.
// 64x64 tile, 256 threads, 4x4 acc per thread. LDS k-major with XOR swizzle.
// ---------------------------------------------------------------------------
__device__ __forceinline__ int swz_(int k) { return ((k >> 2) & 15) << 2; }

__global__ __launch_bounds__(256)
void gemm_abt(const float* __restrict__ A, const float* __restrict__ B,
              const float* __restrict__ bias, float* __restrict__ Cmat,
              int M, int Ngc, int act) {
    __shared__ float As[128 * 64];
    __shared__ float Bs[128 * 64];
    const int tid = threadIdx.x;
    const int bm = blockIdx.x << 6;
    const int bn = blockIdx.y << 6;

    for (int i = tid; i < 2048; i += 256) {
        const int r = i >> 5;
        const int c4 = (i & 31) << 2;
        const int s = swz_(c4);
        float4 v = make_float4(0.f, 0.f, 0.f, 0.f);
        const int gr = bm + r;
        if (gr < M) v = *(const float4*)(A + (size_t)gr * 128 + c4);
        As[(c4 + 0) * 64 + (r ^ s)] = v.x;
        As[(c4 + 1) * 64 + (r ^ s)] = v.y;
        As[(c4 + 2) * 64 + (r ^ s)] = v.z;
        As[(c4 + 3) * 64 + (r ^ s)] = v.w;
    }
    for (int i = tid; i < 2048; i += 256) {
        const int r = i >> 5;
        const int c4 = (i & 31) << 2;
        const int s = swz_(c4);
        float4 v = make_float4(0.f, 0.f, 0.f, 0.f);
        const int gr = bn + r;
        if (gr < Ngc) v = *(const float4*)(B + (size_t)gr * 128 + c4);
        Bs[(c4 + 0) * 64 + (r ^ s)] = v.x;
        Bs[(c4 + 1) * 64 + (r ^ s)] = v.y;
        Bs[(c4 + 2) * 64 + (r ^ s)] = v.z;
        Bs[(c4 + 3) * 64 + (r ^ s)] = v.w;
    }
    __syncthreads();

    const int tr = (tid >> 4) << 2;
    const int tc = (tid & 15) << 2;
    float acc[16] = {};
#pragma unroll 8
    for (int k = 0; k < 128; ++k) {
        const int s = swz_(k);
        const float4 a = *(const float4*)(&As[k * 64 + (tr ^ s)]);
        const float4 b = *(const float4*)(&Bs[k * 64 + (tc ^ s)]);
        acc[0]  += a.x * b.x; acc[1]  += a.x * b.y; acc[2]  += a.x * b.z; acc[3]  += a.x * b.w;
        acc[4]  += a.y * b.x; acc[5]  += a.y * b.y; acc[6]  += a.y * b.z; acc[7]  += a.y * b.w;
        acc[8]  += a.z * b.x; acc[9]  += a.z * b.y; acc[10] += a.z * b.z; acc[11] += a.z * b.w;
        acc[12] += a.w * b.x; acc[13] += a.w * b.y; acc[14] += a.w * b.z; acc[15] += a.w * b.w;
    }
#pragma unroll
    for (int i = 0; i < 4; ++i) {
        const int gr = bm + tr + i;
        if (gr >= M) continue;
#pragma unroll
        for (int j = 0; j < 4; ++j) {
            const int gc = bn + tc + j;
            if (gc >= Ngc) continue;
            float v = acc[i * 4 + j] + (bias ? bias[gc] : 0.f);
            if (act == 1) v = fmaxf(v, 0.f);
            Cmat[(size_t)gr * Ngc + gc] = v;
        }
    }
}

// ---------------------------------------------------------------------------
// GRU gate kernels
// ---------------------------------------------------------------------------
__global__ void gru_gate0(const float* __restrict__ x, int t,
                          const float* __restrict__ Wih0, const float* __restrict__ bih0,
                          const float* __restrict__ gh, float* __restrict__ h) {
    int idx = blockIdx.x * 256 + threadIdx.x;
    if (idx >= NN * HH) return;
    int n = idx >> 7, j = idx & 127;
    float xt = x[(size_t)n * TT + t];
    const float* g = gh + (size_t)n * G3H;
    float gr = fmaf(xt, Wih0[j],          bih0[j])          + g[j];
    float gz = fmaf(xt, Wih0[j + HH],     bih0[j + HH])     + g[j + HH];
    float gn = fmaf(xt, Wih0[j + 2 * HH], bih0[j + 2 * HH]);
    float r = sigmoidf_(gr);
    float z = sigmoidf_(gz);
    float nn2 = tanhf(gn + r * g[j + 2 * HH]);
    h[idx] = (1.f - z) * nn2 + z * h[idx];
}

__global__ void gru_gate1(const float* __restrict__ gx, const float* __restrict__ gh,
                          float* __restrict__ h) {
    int idx = blockIdx.x * 256 + threadIdx.x;
    if (idx >= NN * HH) return;
    int n = idx >> 7, j = idx & 127;
    const float* a = gx + (size_t)n * G3H;
    const float* b = gh + (size_t)n * G3H;
    float r = sigmoidf_(a[j] + b[j]);
    float z = sigmoidf_(a[j + HH] + b[j + HH]);
    float nn2 = tanhf(a[j + 2 * HH] + r * b[j + 2 * HH]);
    h[idx] = (1.f - z) * nn2 + z * h[idx];
}

// ---------------------------------------------------------------------------
// GAT edge kernels
// ---------------------------------------------------------------------------
__global__ void init_neginf(float* p, int n) {
    int i = blockIdx.x * 256 + threadIdx.x;
    if (i < n) p[i] = -INFINITY;
}

__global__ void gat_edge_score(const int* __restrict__ src, const int* __restrict__ dst,
                               const float* __restrict__ ea,
                               const float* __restrict__ xl, const float* __restrict__ xr,
                               const float* __restrict__ We, const float* __restrict__ att,
                               float* __restrict__ sbuf, float* __restrict__ smax) {
    int idx = blockIdx.x * 256 + threadIdx.x;
    if (idx >= EE * NHEADS) return;
    int e = idx >> 2, hd = idx & 3;
    int sN = src[e], dN = dst[e];
    float eav = ea[e];
    const float* pl = xl + (size_t)sN * HH + hd * CH;
    const float* pr = xr + (size_t)dN * HH + hd * CH;
    const float* pw = We + hd * CH;
    const float* pa = att + hd * CH;
    float acc = 0.f;
#pragma unroll
    for (int c4 = 0; c4 < 8; ++c4) {
        float4 vl = *(const float4*)(pl + c4 * 4);
        float4 vr = *(const float4*)(pr + c4 * 4);
        float4 vw = *(const float4*)(pw + c4 * 4);
        float4 va = *(const float4*)(pa + c4 * 4);
        float m;
        m = vl.x + vr.x + eav * vw.x; m = (m > 0.f) ? m : 0.2f * m; acc += m * va.x;
        m = vl.y + vr.y + eav * vw.y; m = (m > 0.f) ? m : 0.2f * m; acc += m * va.y;
        m = vl.z + vr.z + eav * vw.z; m = (m > 0.f) ? m : 0.2f * m; acc += m * va.z;
        m = vl.w + vr.w + eav * vw.w; m = (m > 0.f) ? m : 0.2f * m; acc += m * va.w;
    }
    sbuf[idx] = acc;
    atomicMaxFloat(&smax[dN * NHEADS + hd], acc);
}

__global__ void gat_edge_exp(const int* __restrict__ dst, const float* __restrict__ sbuf,
                             const float* __restrict__ smax, float* __restrict__ esbuf,
                             float* __restrict__ denom) {
    int idx = blockIdx.x * 256 + threadIdx.x;
    if (idx >= EE * NHEADS) return;
    int e = idx >> 2, hd = idx & 3;
    int dN = dst[e];
    float es = expf(sbuf[idx] - smax[dN * NHEADS + hd]);
    esbuf[idx] = es;
    atomicAdd(&denom[dN * NHEADS + hd], es);
}

__global__ void gat_edge_scatter(const int* __restrict__ src, const int* __restrict__ dst,
                                 const float* __restrict__ esbuf, const float* __restrict__ denom,
                                 const float* __restrict__ xl, float* __restrict__ z) {
    int idx = blockIdx.x * 256 + threadIdx.x;
    if (idx >= EE * NHEADS) return;
    int e = idx >> 2, hd = idx & 3;
    int sN = src[e], dN = dst[e];
    float alpha = esbuf[idx] / fmaxf(denom[dN * NHEADS + hd], 1e-16f);
    const float* pl = xl + (size_t)sN * HH + hd * CH;
    float* pz = z + (size_t)dN * HH + hd * CH;
#pragma unroll
    for (int c4 = 0; c4 < 8; ++c4) {
        float4 vl = *(const float4*)(pl + c4 * 4);
        atomicAdd(&pz[c4 * 4 + 0], alpha * vl.x);
        atomicAdd(&pz[c4 * 4 + 1], alpha * vl.y);
        atomicAdd(&pz[c4 * 4 + 2], alpha * vl.z);
        atomicAdd(&pz[c4 * 4 + 3], alpha * vl.w);
    }
}

// ---------------------------------------------------------------------------
// LayerNorm + ELU + residual (in-place on h). One wave (64 lanes) per node.
// ---------------------------------------------------------------------------
__global__ __launch_bounds__(256)
void ln_elu_res(const float* __restrict__ z, const float* __restrict__ gbias,
                const float* __restrict__ gamma, const float* __restrict__ beta,
                float* __restrict__ h) {
    int gtid = blockIdx.x * 256 + threadIdx.x;
    int n = gtid >> 6;
    int l = gtid & 63;
    if (n >= NN) return;
    float v0 = z[(size_t)n * HH + l] + gbias[l];
    float v1 = z[(size_t)n * HH + l + 64] + gbias[l + 64];
    float sum = v0 + v1;
    float ssq = v0 * v0 + v1 * v1;
#pragma unroll
    for (int m = 1; m < 64; m <<= 1) {
        sum += __shfl_xor(sum, m);
        ssq += __shfl_xor(ssq, m);
    }
    float mean = sum * (1.f / 128.f);
    float var = ssq * (1.f / 128.f) - mean * mean;
    float inv = rsqrtf(var + 1e-5f);
    float y0 = (v0 - mean) * inv * gamma[l] + beta[l];
    float y1 = (v1 - mean) * inv * gamma[l + 64] + beta[l + 64];
    y0 = (y0 > 0.f) ? y0 : expm1f(y0);
    y1 = (y1 > 0.f) ? y1 : expm1f(y1);
    h[(size_t)n * HH + l]      = y0 + h[(size_t)n * HH + l];
    h[(size_t)n * HH + l + 64] = y1 + h[(size_t)n * HH + l + 64];
}

// ---------------------------------------------------------------------------
// Small transpose: dst[c*R + r] = src[r*Cc + c]
// ---------------------------------------------------------------------------
__global__ void transpose_k(const float* __restrict__ src, float* __restrict__ dst,
                            int R, int Cc) {
    int idx = blockIdx.x * 256 + threadIdx.x;
    if (idx >= R * Cc) return;
    int r = idx / Cc, c = idx % Cc;
    dst[(size_t)c * R + r] = src[(size_t)r * Cc + c];
}

// ---------------------------------------------------------------------------
extern "C" void kernel_launch(void* const* d_in, const int* in_sizes, int n_in,
                              void* d_out, int out_size, void* d_ws, size_t ws_size,
                              hipStream_t stream) {
    const float* x     = (const float*)d_in[0];
    const int*   ei    = (const int*)d_in[1];
    const int*   src   = ei;
    const int*   dst   = ei + EE;
    const float* ea    = (const float*)d_in[2];
    const float* Wih0  = (const float*)d_in[3];
    const float* Whh0  = (const float*)d_in[4];
    const float* bih0  = (const float*)d_in[5];
    const float* bhh0  = (const float*)d_in[6];
    const float* Wih1  = (const float*)d_in[7];
    const float* Whh1  = (const float*)d_in[8];
    const float* bih1  = (const float*)d_in[9];
    const float* bhh1  = (const float*)d_in[10];
    const float* gWl   = (const float*)d_in[11];
    const float* gbl   = (const float*)d_in[12];
    const float* gWr   = (const float*)d_in[13];
    const float* gbr   = (const float*)d_in[14];
    const float* gWe   = (const float*)d_in[15];
    const float* gatt  = (const float*)d_in[16];
    const float* gbias = (const float*)d_in[17];
    const float* lng   = (const float*)d_in[18];
    const float* lnb   = (const float*)d_in[19];
    const float* fcW1  = (const float*)d_in[20];
    const float* fcb1  = (const float*)d_in[21];
    const float* fcW2  = (const float*)d_in[22];
    const float* fcb2  = (const float*)d_in[23];
    float* out = (float*)d_out;
    float* ws  = (float*)d_ws;

    const size_t NH  = (size_t)NN * HH;       // 6.4M floats
    const size_t N3H = (size_t)NN * G3H;      // 19.2M floats
    float* h0   = ws;
    float* h1   = h0 + NH;
    float* bufA = h1 + NH;                    // gh0 / gx1; later xl|xr|z
    float* bufB = bufA + N3H;                 // gh1; later sbuf|esbuf|smax|denom|hfc
    float* WlT  = bufB + N3H;                 // 3*16384
    float* WrT  = WlT + 3 * 16384;
    float* W1T  = WrT + 3 * 16384;            // 16384
    float* W2T  = W1T + 16384;                // 12*128

    // GAT-phase aliases
    float* xl    = bufA;
    float* xr    = bufA + NH;
    float* zb    = bufA + 2 * NH;
    float* sbuf  = bufB;
    float* esbuf = bufB + (size_t)EE * NHEADS;
    float* smax  = bufB + (size_t)2 * EE * NHEADS;
    float* denom = smax + (size_t)NN * NHEADS;
    float* hfc   = denom + (size_t)NN * NHEADS;

    // --- pre-transpose weights used un-transposed by the reference ---
    for (int l = 0; l < LLAYERS; ++l) {
        transpose_k<<<64, 256, 0, stream>>>(gWl + (size_t)l * 16384, WlT + (size_t)l * 16384, 128, 128);
        transpose_k<<<64, 256, 0, stream>>>(gWr + (size_t)l * 16384, WrT + (size_t)l * 16384, 128, 128);
    }
    transpose_k<<<64, 256, 0, stream>>>(fcW1, W1T, 128, 128);
    transpose_k<<<6, 256, 0, stream>>>(fcW2, W2T, 128, 12);

    // --- GRU (fused over time: layer0 then layer1 each step) ---
    hipMemsetAsync(h0, 0, NH * sizeof(float), stream);
    hipMemsetAsync(h1, 0, NH * sizeof(float), stream);

    dim3 g384((NN + 63) / 64, G3H / 64);
    dim3 g128((NN + 63) / 64, HH / 64);
    dim3 g12((NN + 63) / 64, 1);
    int gateBlocks = (NN * HH + 255) / 256;
    for (int t = 0; t < TT; ++t) {
        gemm_abt<<<g384, 256, 0, stream>>>(h0, Whh0, bhh0, bufA, NN, G3H, 0);
        gru_gate0<<<gateBlocks, 256, 0, stream>>>(x, t, Wih0, bih0, bufA, h0);
        gemm_abt<<<g384, 256, 0, stream>>>(h0, Wih1, bih1, bufA, NN, G3H, 0);
        gemm_abt<<<g384, 256, 0, stream>>>(h1, Whh1, bhh1, bufB, NN, G3H, 0);
        gru_gate1<<<gateBlocks, 256, 0, stream>>>(bufA, bufB, h1);
    }

    // --- GAT layers ---
    int edgeBlocks = (EE * NHEADS + 255) / 256;
    int lnBlocks = (NN * 64 + 255) / 256;
    for (int l = 0; l < LLAYERS; ++l) {
        gemm_abt<<<g128, 256, 0, stream>>>(h1, WlT + (size_t)l * 16384, gbl + l * HH, xl, NN, HH, 0);
        gemm_abt<<<g128, 256, 0, stream>>>(h1, WrT + (size_t)l * 16384, gbr + l * HH, xr, NN, HH, 0);
        hipMemsetAsync(zb, 0, NH * sizeof(float), stream);
        hipMemsetAsync(denom, 0, (size_t)NN * NHEADS * sizeof(float), stream);
        init_neginf<<<(NN * NHEADS + 255) / 256, 256, 0, stream>>>(smax, NN * NHEADS);
        gat_edge_score<<<edgeBlocks, 256, 0, stream>>>(src, dst, ea, xl, xr,
                                                       gWe + l * HH, gatt + l * HH, sbuf, smax);
        gat_edge_exp<<<edgeBlocks, 256, 0, stream>>>(dst, sbuf, smax, esbuf, denom);
        gat_edge_scatter<<<edgeBlocks, 256, 0, stream>>>(src, dst, esbuf, denom, xl, zb);
        ln_elu_res<<<lnBlocks, 256, 0, stream>>>(zb, gbias + l * HH, lng + l * HH, lnb + l * HH, h1);
    }

    // --- FC head ---
    gemm_abt<<<g128, 256, 0, stream>>>(h1, W1T, fcb1, hfc, NN, HH, 1);
    gemm_abt<<<g12, 256, 0, stream>>>(hfc, W2T, fcb2, out, NN, OO, 0);
}

// Round 2
// 6676.116 us; speedup vs baseline: 3.4982x; 3.4982x over previous
//
#include <hip/hip_runtime.h>

#define NN 50000
#define EE 800000
#define TT 12
#define HH 128
#define NHEADS 4
#define CH 32
#define LLAYERS 3
#define OO 12
#define G3H 384

__device__ __forceinline__ float sigmoidf_(float x) { return 1.f / (1.f + expf(-x)); }

// ---------------------------------------------------------------------------
// Generic fp32 GEMM: C[M,Ngc] = A[M,128] * B[Ngc,128]^T + bias, optional relu.
// 64x64 tile, 256 threads, 4x4 acc per thread. LDS k-major with XOR swizzle.
// ---------------------------------------------------------------------------
__device__ __forceinline__ int swz_(int k) { return ((k >> 2) & 15) << 2; }

__global__ __launch_bounds__(256)
void gemm_abt(const float* __restrict__ A, const float* __restrict__ B,
              const float* __restrict__ bias, float* __restrict__ Cmat,
              int M, int Ngc, int act) {
    __shared__ float As[128 * 64];
    __shared__ float Bs[128 * 64];
    const int tid = threadIdx.x;
    const int bm = blockIdx.x << 6;
    const int bn = blockIdx.y << 6;

    for (int i = tid; i < 2048; i += 256) {
        const int r = i >> 5;
        const int c4 = (i & 31) << 2;
        const int s = swz_(c4);
        float4 v = make_float4(0.f, 0.f, 0.f, 0.f);
        const int gr = bm + r;
        if (gr < M) v = *(const float4*)(A + (size_t)gr * 128 + c4);
        As[(c4 + 0) * 64 + (r ^ s)] = v.x;
        As[(c4 + 1) * 64 + (r ^ s)] = v.y;
        As[(c4 + 2) * 64 + (r ^ s)] = v.z;
        As[(c4 + 3) * 64 + (r ^ s)] = v.w;
    }
    for (int i = tid; i < 2048; i += 256) {
        const int r = i >> 5;
        const int c4 = (i & 31) << 2;
        const int s = swz_(c4);
        float4 v = make_float4(0.f, 0.f, 0.f, 0.f);
        const int gr = bn + r;
        if (gr < Ngc) v = *(const float4*)(B + (size_t)gr * 128 + c4);
        Bs[(c4 + 0) * 64 + (r ^ s)] = v.x;
        Bs[(c4 + 1) * 64 + (r ^ s)] = v.y;
        Bs[(c4 + 2) * 64 + (r ^ s)] = v.z;
        Bs[(c4 + 3) * 64 + (r ^ s)] = v.w;
    }
    __syncthreads();

    const int tr = (tid >> 4) << 2;
    const int tc = (tid & 15) << 2;
    float acc[16] = {};
#pragma unroll 8
    for (int k = 0; k < 128; ++k) {
        const int s = swz_(k);
        const float4 a = *(const float4*)(&As[k * 64 + (tr ^ s)]);
        const float4 b = *(const float4*)(&Bs[k * 64 + (tc ^ s)]);
        acc[0]  += a.x * b.x; acc[1]  += a.x * b.y; acc[2]  += a.x * b.z; acc[3]  += a.x * b.w;
        acc[4]  += a.y * b.x; acc[5]  += a.y * b.y; acc[6]  += a.y * b.z; acc[7]  += a.y * b.w;
        acc[8]  += a.z * b.x; acc[9]  += a.z * b.y; acc[10] += a.z * b.z; acc[11] += a.z * b.w;
        acc[12] += a.w * b.x; acc[13] += a.w * b.y; acc[14] += a.w * b.z; acc[15] += a.w * b.w;
    }
#pragma unroll
    for (int i = 0; i < 4; ++i) {
        const int gr = bm + tr + i;
        if (gr >= M) continue;
#pragma unroll
        for (int j = 0; j < 4; ++j) {
            const int gc = bn + tc + j;
            if (gc >= Ngc) continue;
            float v = acc[i * 4 + j] + (bias ? bias[gc] : 0.f);
            if (act == 1) v = fmaxf(v, 0.f);
            Cmat[(size_t)gr * Ngc + gc] = v;
        }
    }
}

// ---------------------------------------------------------------------------
// GRU gate kernels
// ---------------------------------------------------------------------------
__global__ void gru_gate0(const float* __restrict__ x, int t,
                          const float* __restrict__ Wih0, const float* __restrict__ bih0,
                          const float* __restrict__ gh, float* __restrict__ h) {
    int idx = blockIdx.x * 256 + threadIdx.x;
    if (idx >= NN * HH) return;
    int n = idx >> 7, j = idx & 127;
    float xt = x[(size_t)n * TT + t];
    const float* g = gh + (size_t)n * G3H;
    float gr = fmaf(xt, Wih0[j],          bih0[j])          + g[j];
    float gz = fmaf(xt, Wih0[j + HH],     bih0[j + HH])     + g[j + HH];
    float gn = fmaf(xt, Wih0[j + 2 * HH], bih0[j + 2 * HH]);
    float r = sigmoidf_(gr);
    float z = sigmoidf_(gz);
    float nn2 = tanhf(gn + r * g[j + 2 * HH]);
    h[idx] = (1.f - z) * nn2 + z * h[idx];
}

__global__ void gru_gate1(const float* __restrict__ gx, const float* __restrict__ gh,
                          float* __restrict__ h) {
    int idx = blockIdx.x * 256 + threadIdx.x;
    if (idx >= NN * HH) return;
    int n = idx >> 7, j = idx & 127;
    const float* a = gx + (size_t)n * G3H;
    const float* b = gh + (size_t)n * G3H;
    float r = sigmoidf_(a[j] + b[j]);
    float z = sigmoidf_(a[j + HH] + b[j + HH]);
    float nn2 = tanhf(a[j + 2 * HH] + r * b[j + 2 * HH]);
    h[idx] = (1.f - z) * nn2 + z * h[idx];
}

// ---------------------------------------------------------------------------
// CSR build (by dst). cursor doubles as degree-histogram then write cursor.
// ---------------------------------------------------------------------------
__global__ void csr_count(const int* __restrict__ dst, int* __restrict__ cursor) {
    int e = blockIdx.x * 256 + threadIdx.x;
    if (e < EE) atomicAdd(&cursor[dst[e]], 1);
}

__global__ __launch_bounds__(1024)
void csr_scan(int* __restrict__ cursor, int* __restrict__ rowptr) {
    __shared__ int sm[1024];
    __shared__ int carry_s;
    if (threadIdx.x == 0) carry_s = 0;
    __syncthreads();
    for (int base = 0; base < NN; base += 1024) {
        int i = base + threadIdx.x;
        int v = (i < NN) ? cursor[i] : 0;
        int c = carry_s;
        __syncthreads();
        sm[threadIdx.x] = v;
        __syncthreads();
        for (int off = 1; off < 1024; off <<= 1) {
            int t = (threadIdx.x >= off) ? sm[threadIdx.x - off] : 0;
            __syncthreads();
            sm[threadIdx.x] += t;
            __syncthreads();
        }
        int excl = c + sm[threadIdx.x] - v;
        if (i < NN) { rowptr[i] = excl; cursor[i] = excl; }
        if (threadIdx.x == 0) carry_s = c + sm[1023];
        __syncthreads();
    }
    if (threadIdx.x == 0) rowptr[NN] = carry_s;
}

__global__ void csr_fill(const int* __restrict__ dst, int* __restrict__ cursor,
                         int* __restrict__ eidx) {
    int e = blockIdx.x * 256 + threadIdx.x;
    if (e >= EE) return;
    int pos = atomicAdd(&cursor[dst[e]], 1);
    eidx[pos] = e;
}

// ---------------------------------------------------------------------------
// GAT edge scores: one wave per edge, coalesced 512B row reads, shfl reduce.
// sbuf[e*4 + h] = sum_c leaky(xl[src,c]+xr[dst,c]+ea*We[c]) * att[c] over head h
// ---------------------------------------------------------------------------
__global__ __launch_bounds__(256)
void gat_score(const int* __restrict__ src, const int* __restrict__ dst,
               const float* __restrict__ ea,
               const float* __restrict__ xl, const float* __restrict__ xr,
               const float* __restrict__ We, const float* __restrict__ att,
               float* __restrict__ sbuf) {
    int wid = (blockIdx.x * 256 + threadIdx.x) >> 6;   // edge id
    int lane = threadIdx.x & 63;
    if (wid >= EE) return;
    int sN = src[wid], dN = dst[wid];
    float eav = ea[wid];
    const float* pl = xl + (size_t)sN * HH;
    const float* pr = xr + (size_t)dN * HH;
    float mA = pl[lane] + pr[lane] + eav * We[lane];
    float mB = pl[lane + 64] + pr[lane + 64] + eav * We[lane + 64];
    mA = (mA > 0.f) ? mA : 0.2f * mA;
    mB = (mB > 0.f) ? mB : 0.2f * mB;
    float sA = mA * att[lane];
    float sB = mB * att[lane + 64];
#pragma unroll
    for (int off = 1; off < 32; off <<= 1) {
        sA += __shfl_xor(sA, off);
        sB += __shfl_xor(sB, off);
    }
    if ((lane & 31) == 0) {
        int h01 = lane >> 5;                            // 0 or 1
        sbuf[(size_t)wid * 4 + h01]     = sA;           // heads 0/1
        sbuf[(size_t)wid * 4 + 2 + h01] = sB;           // heads 2/3
    }
}

// ---------------------------------------------------------------------------
// Per-dst-node aggregation + bias + LayerNorm + ELU + residual (fused).
// One 64-lane wave per node; lane owns channels (lane) and (lane+64).
// out = (sum_e exp(s-smax)*xl[src]) / (sum_e exp(s-smax))
// ---------------------------------------------------------------------------
__global__ __launch_bounds__(256)
void gat_aggregate(const int* __restrict__ rowptr, const int* __restrict__ eidx,
                   const int* __restrict__ src, const float* __restrict__ sbuf,
                   const float* __restrict__ xl,
                   const float* __restrict__ gbias, const float* __restrict__ gamma,
                   const float* __restrict__ beta, float* __restrict__ h) {
    int node = (blockIdx.x * 256 + threadIdx.x) >> 6;
    int lane = threadIdx.x & 63;
    if (node >= NN) return;
    int beg = rowptr[node], end = rowptr[node + 1];

    // pass 1: per-head max over this node's edges
    float m0 = -INFINITY, m1 = -INFINITY, m2 = -INFINITY, m3 = -INFINITY;
    for (int i = beg + lane; i < end; i += 64) {
        int eid = eidx[i];
        float4 s4 = *(const float4*)(sbuf + (size_t)eid * 4);
        m0 = fmaxf(m0, s4.x); m1 = fmaxf(m1, s4.y);
        m2 = fmaxf(m2, s4.z); m3 = fmaxf(m3, s4.w);
    }
#pragma unroll
    for (int off = 1; off < 64; off <<= 1) {
        m0 = fmaxf(m0, __shfl_xor(m0, off));
        m1 = fmaxf(m1, __shfl_xor(m1, off));
        m2 = fmaxf(m2, __shfl_xor(m2, off));
        m3 = fmaxf(m3, __shfl_xor(m3, off));
    }
    const int hA = lane >> 5;            // head of channel `lane`   (0 or 1)
    const float mxA = hA ? m1 : m0;
    const float mxB = hA ? m3 : m2;      // head of channel lane+64  (2 or 3)

    // pass 2: unnormalized weighted sum + denom (same value across head group)
    float accA = 0.f, accB = 0.f, denA = 0.f, denB = 0.f;
    for (int i = beg; i < end; ++i) {
        int eid = eidx[i];
        int sN = src[eid];
        float eA = expf(sbuf[(size_t)eid * 4 + hA] - mxA);
        float eB = expf(sbuf[(size_t)eid * 4 + 2 + hA] - mxB);
        const float* pl = xl + (size_t)sN * HH;
        accA += eA * pl[lane];
        accB += eB * pl[lane + 64];
        denA += eA; denB += eB;
    }
    float vA = accA / fmaxf(denA, 1e-16f) + gbias[lane];
    float vB = accB / fmaxf(denB, 1e-16f) + gbias[lane + 64];

    // fused LayerNorm + ELU + residual
    float sum = vA + vB;
    float ssq = vA * vA + vB * vB;
#pragma unroll
    for (int off = 1; off < 64; off <<= 1) {
        sum += __shfl_xor(sum, off);
        ssq += __shfl_xor(ssq, off);
    }
    float mean = sum * (1.f / 128.f);
    float var = ssq * (1.f / 128.f) - mean * mean;
    float inv = rsqrtf(var + 1e-5f);
    float yA = (vA - mean) * inv * gamma[lane] + beta[lane];
    float yB = (vB - mean) * inv * gamma[lane + 64] + beta[lane + 64];
    yA = (yA > 0.f) ? yA : expm1f(yA);
    yB = (yB > 0.f) ? yB : expm1f(yB);
    h[(size_t)node * HH + lane]      += yA;
    h[(size_t)node * HH + lane + 64] += yB;
}

// ---------------------------------------------------------------------------
// Small transpose: dst[c*R + r] = src[r*Cc + c]
// ---------------------------------------------------------------------------
__global__ void transpose_k(const float* __restrict__ src, float* __restrict__ dst,
                            int R, int Cc) {
    int idx = blockIdx.x * 256 + threadIdx.x;
    if (idx >= R * Cc) return;
    int r = idx / Cc, c = idx % Cc;
    dst[(size_t)c * R + r] = src[(size_t)r * Cc + c];
}

// ---------------------------------------------------------------------------
extern "C" void kernel_launch(void* const* d_in, const int* in_sizes, int n_in,
                              void* d_out, int out_size, void* d_ws, size_t ws_size,
                              hipStream_t stream) {
    const float* x     = (const float*)d_in[0];
    const int*   ei    = (const int*)d_in[1];
    const int*   src   = ei;
    const int*   dst   = ei + EE;
    const float* ea    = (const float*)d_in[2];
    const float* Wih0  = (const float*)d_in[3];
    const float* Whh0  = (const float*)d_in[4];
    const float* bih0  = (const float*)d_in[5];
    const float* bhh0  = (const float*)d_in[6];
    const float* Wih1  = (const float*)d_in[7];
    const float* Whh1  = (const float*)d_in[8];
    const float* bih1  = (const float*)d_in[9];
    const float* bhh1  = (const float*)d_in[10];
    const float* gWl   = (const float*)d_in[11];
    const float* gbl   = (const float*)d_in[12];
    const float* gWr   = (const float*)d_in[13];
    const float* gbr   = (const float*)d_in[14];
    const float* gWe   = (const float*)d_in[15];
    const float* gatt  = (const float*)d_in[16];
    const float* gbias = (const float*)d_in[17];
    const float* lng   = (const float*)d_in[18];
    const float* lnb   = (const float*)d_in[19];
    const float* fcW1  = (const float*)d_in[20];
    const float* fcb1  = (const float*)d_in[21];
    const float* fcW2  = (const float*)d_in[22];
    const float* fcb2  = (const float*)d_in[23];
    float* out = (float*)d_out;
    float* ws  = (float*)d_ws;

    const size_t NH  = (size_t)NN * HH;       // 6.4M floats
    const size_t N3H = (size_t)NN * G3H;      // 19.2M floats
    float* h0   = ws;
    float* h1   = h0 + NH;
    float* bufA = h1 + NH;                    // GRU: gh0/gx1; GAT: xl|xr
    float* bufB = bufA + N3H;                 // GRU: gh1; GAT: sbuf|CSR|hfc
    float* WlT  = bufB + N3H;                 // 3*16384
    float* WrT  = WlT + 3 * 16384;
    float* W1T  = WrT + 3 * 16384;            // 16384
    float* W2T  = W1T + 16384;                // 12*128

    // GAT-phase aliases
    float* xl     = bufA;
    float* xr     = bufA + NH;
    float* sbuf   = bufB;                                   // EE*4 floats
    int*   rowptr = (int*)(bufB + (size_t)EE * NHEADS);     // NN+1
    int*   cursor = rowptr + (NN + 1);                      // NN
    int*   eidx   = cursor + NN;                            // EE
    float* hfc    = (float*)(eidx + EE);                    // NN*HH

    // --- pre-transpose weights used un-transposed by the reference ---
    for (int l = 0; l < LLAYERS; ++l) {
        transpose_k<<<64, 256, 0, stream>>>(gWl + (size_t)l * 16384, WlT + (size_t)l * 16384, 128, 128);
        transpose_k<<<64, 256, 0, stream>>>(gWr + (size_t)l * 16384, WrT + (size_t)l * 16384, 128, 128);
    }
    transpose_k<<<64, 256, 0, stream>>>(fcW1, W1T, 128, 128);
    transpose_k<<<6, 256, 0, stream>>>(fcW2, W2T, 128, 12);

    // --- GRU (fused over time: layer0 then layer1 each step) ---
    hipMemsetAsync(h0, 0, NH * sizeof(float), stream);
    hipMemsetAsync(h1, 0, NH * sizeof(float), stream);

    dim3 g384((NN + 63) / 64, G3H / 64);
    dim3 g128((NN + 63) / 64, HH / 64);
    dim3 g12((NN + 63) / 64, 1);
    int gateBlocks = (NN * HH + 255) / 256;
    for (int t = 0; t < TT; ++t) {
        gemm_abt<<<g384, 256, 0, stream>>>(h0, Whh0, bhh0, bufA, NN, G3H, 0);
        gru_gate0<<<gateBlocks, 256, 0, stream>>>(x, t, Wih0, bih0, bufA, h0);
        gemm_abt<<<g384, 256, 0, stream>>>(h0, Wih1, bih1, bufA, NN, G3H, 0);
        gemm_abt<<<g384, 256, 0, stream>>>(h1, Whh1, bhh1, bufB, NN, G3H, 0);
        gru_gate1<<<gateBlocks, 256, 0, stream>>>(bufA, bufB, h1);
    }

    // --- CSR by dst (topology shared by all 3 GAT layers) ---
    hipMemsetAsync(cursor, 0, NN * sizeof(int), stream);
    csr_count<<<(EE + 255) / 256, 256, 0, stream>>>(dst, cursor);
    csr_scan<<<1, 1024, 0, stream>>>(cursor, rowptr);
    csr_fill<<<(EE + 255) / 256, 256, 0, stream>>>(dst, cursor, eidx);

    // --- GAT layers ---
    int scoreBlocks = (EE * 64 + 255) / 256;
    int aggBlocks = (NN * 64 + 255) / 256;
    for (int l = 0; l < LLAYERS; ++l) {
        gemm_abt<<<g128, 256, 0, stream>>>(h1, WlT + (size_t)l * 16384, gbl + l * HH, xl, NN, HH, 0);
        gemm_abt<<<g128, 256, 0, stream>>>(h1, WrT + (size_t)l * 16384, gbr + l * HH, xr, NN, HH, 0);
        gat_score<<<scoreBlocks, 256, 0, stream>>>(src, dst, ea, xl, xr,
                                                   gWe + l * HH, gatt + l * HH, sbuf);
        gat_aggregate<<<aggBlocks, 256, 0, stream>>>(rowptr, eidx, src, sbuf, xl,
                                                     gbias + l * HH, lng + l * HH, lnb + l * HH, h1);
    }

    // --- FC head ---
    gemm_abt<<<g128, 256, 0, stream>>>(h1, W1T, fcb1, hfc, NN, HH, 1);
    gemm_abt<<<g12, 256, 0, stream>>>(hfc, W2T, fcb2, out, NN, OO, 0);
}

// Round 3
// 3071.164 us; speedup vs baseline: 7.6043x; 2.1738x over previous
//
#include <hip/hip_runtime.h>

#define NN 50000
#define EE 800000
#define TT 12
#define HH 128
#define NHEADS 4
#define CH 32
#define LLAYERS 3
#define OO 12
#define G3H 384

typedef __attribute__((ext_vector_type(8))) short short8;    // 8 bf16 = 4 VGPRs
typedef __attribute__((ext_vector_type(4))) float float4v;   // MFMA acc

typedef unsigned short ushort_t;

__device__ __forceinline__ float sigmoidf_(float x) { return 1.f / (1.f + expf(-x)); }

__device__ __forceinline__ ushort_t f2b(float f) {   // fp32 -> bf16 RNE
    union { float f; unsigned u; } v; v.f = f;
    unsigned u = v.u;
    unsigned r = (u + 0x7FFFu + ((u >> 16) & 1u)) >> 16;
    return (ushort_t)r;
}
__device__ __forceinline__ float b2f(ushort_t b) {
    union { unsigned u; float f; } v; v.u = ((unsigned)b) << 16; return v.f;
}
__device__ __forceinline__ short8 ld8(const ushort_t* p) { return *(const short8*)p; }

// ---------------------------------------------------------------------------
// GRU step, layer 0: gh0 = h0 @ Whh0^T (MFMA) fused with gate0 -> h0'
// grid 782 x 256thr; wave owns 16 rows x 384 cols; K=128.
// ---------------------------------------------------------------------------
__global__ __launch_bounds__(256)
void gru_step0(const float* __restrict__ x, int t,
               ushort_t* __restrict__ h0b, float* __restrict__ h0f,
               const ushort_t* __restrict__ Whhb, const float* __restrict__ Wih,
               const float* __restrict__ bih, const float* __restrict__ bhh) {
    const int wave = threadIdx.x >> 6, lane = threadIdx.x & 63;
    const int r0 = (blockIdx.x * 4 + wave) * 16;
    const int col = lane & 15, kg = lane >> 4;
    const int arow = min(r0 + col, NN - 1);
    short8 a[4];
#pragma unroll
    for (int ks = 0; ks < 4; ++ks)
        a[ks] = ld8(h0b + (size_t)arow * HH + ks * 32 + kg * 8);
    float xv[4];
#pragma unroll
    for (int i = 0; i < 4; ++i) {
        int node = r0 + kg * 4 + i;
        xv[i] = (node < NN) ? x[(size_t)node * TT + t] : 0.f;
    }
    for (int j0 = 0; j0 < 8; ++j0) {
        float4v aR = {0,0,0,0}, aZ = {0,0,0,0}, aN = {0,0,0,0};
        const ushort_t* bp = Whhb + (size_t)(j0 * 16 + col) * HH + kg * 8;
#pragma unroll
        for (int ks = 0; ks < 4; ++ks) {
            short8 bR = ld8(bp + ks * 32);
            short8 bZ = ld8(bp + 128 * HH + ks * 32);
            short8 bN = ld8(bp + 256 * HH + ks * 32);
            aR = __builtin_amdgcn_mfma_f32_16x16x32_bf16(a[ks], bR, aR, 0, 0, 0);
            aZ = __builtin_amdgcn_mfma_f32_16x16x32_bf16(a[ks], bZ, aZ, 0, 0, 0);
            aN = __builtin_amdgcn_mfma_f32_16x16x32_bf16(a[ks], bN, aN, 0, 0, 0);
        }
        const int j = j0 * 16 + col;
        const float wR = Wih[j], wZ = Wih[j + 128], wN = Wih[j + 256];
        const float biR = bih[j], biZ = bih[j + 128], biN = bih[j + 256];
        const float bhR = bhh[j], bhZ = bhh[j + 128], bhN = bhh[j + 256];
#pragma unroll
        for (int i = 0; i < 4; ++i) {
            const int node = r0 + kg * 4 + i;
            if (node >= NN) continue;
            const size_t off = (size_t)node * HH + j;
            const float hold = h0f[off];
            float r = sigmoidf_(xv[i] * wR + biR + aR[i] + bhR);
            float z = sigmoidf_(xv[i] * wZ + biZ + aZ[i] + bhZ);
            float nn2 = tanhf(xv[i] * wN + biN + r * (aN[i] + bhN));
            float hn = (1.f - z) * nn2 + z * hold;
            h0f[off] = hn;
            h0b[off] = f2b(hn);
        }
    }
}

// ---------------------------------------------------------------------------
// GRU step, layer 1: gx1 = h0' @ Wih1^T, gh1 = h1 @ Whh1^T, fused gate1 -> h1'
// ---------------------------------------------------------------------------
__global__ __launch_bounds__(256)
void gru_step1(const ushort_t* __restrict__ h0b,
               ushort_t* __restrict__ h1b, float* __restrict__ h1f,
               const ushort_t* __restrict__ Wihb, const ushort_t* __restrict__ Whhb,
               const float* __restrict__ bih, const float* __restrict__ bhh) {
    const int wave = threadIdx.x >> 6, lane = threadIdx.x & 63;
    const int r0 = (blockIdx.x * 4 + wave) * 16;
    const int col = lane & 15, kg = lane >> 4;
    const int arow = min(r0 + col, NN - 1);
    short8 a0[4], a1[4];
#pragma unroll
    for (int ks = 0; ks < 4; ++ks) {
        a0[ks] = ld8(h0b + (size_t)arow * HH + ks * 32 + kg * 8);
        a1[ks] = ld8(h1b + (size_t)arow * HH + ks * 32 + kg * 8);
    }
    for (int j0 = 0; j0 < 8; ++j0) {
        float4v xR = {0,0,0,0}, xZ = {0,0,0,0}, xN = {0,0,0,0};
        float4v hR = {0,0,0,0}, hZ = {0,0,0,0}, hN = {0,0,0,0};
        const ushort_t* bpx = Wihb + (size_t)(j0 * 16 + col) * HH + kg * 8;
        const ushort_t* bph = Whhb + (size_t)(j0 * 16 + col) * HH + kg * 8;
#pragma unroll
        for (int ks = 0; ks < 4; ++ks) {
            xR = __builtin_amdgcn_mfma_f32_16x16x32_bf16(a0[ks], ld8(bpx + ks * 32), xR, 0, 0, 0);
            xZ = __builtin_amdgcn_mfma_f32_16x16x32_bf16(a0[ks], ld8(bpx + 128 * HH + ks * 32), xZ, 0, 0, 0);
            xN = __builtin_amdgcn_mfma_f32_16x16x32_bf16(a0[ks], ld8(bpx + 256 * HH + ks * 32), xN, 0, 0, 0);
            hR = __builtin_amdgcn_mfma_f32_16x16x32_bf16(a1[ks], ld8(bph + ks * 32), hR, 0, 0, 0);
            hZ = __builtin_amdgcn_mfma_f32_16x16x32_bf16(a1[ks], ld8(bph + 128 * HH + ks * 32), hZ, 0, 0, 0);
            hN = __builtin_amdgcn_mfma_f32_16x16x32_bf16(a1[ks], ld8(bph + 256 * HH + ks * 32), hN, 0, 0, 0);
        }
        const int j = j0 * 16 + col;
        const float biR = bih[j], biZ = bih[j + 128], biN = bih[j + 256];
        const float bhR = bhh[j], bhZ = bhh[j + 128], bhN = bhh[j + 256];
#pragma unroll
        for (int i = 0; i < 4; ++i) {
            const int node = r0 + kg * 4 + i;
            if (node >= NN) continue;
            const size_t off = (size_t)node * HH + j;
            const float hold = h1f[off];
            float r = sigmoidf_(xR[i] + biR + hR[i] + bhR);
            float z = sigmoidf_(xZ[i] + biZ + hZ[i] + bhZ);
            float nn2 = tanhf(xN[i] + biN + r * (hN[i] + bhN));
            float hn = (1.f - z) * nn2 + z * hold;
            h1f[off] = hn;
            h1b[off] = f2b(hn);
        }
    }
}

// ---------------------------------------------------------------------------
// bf16 MFMA GEMM, N=128, K=128: C = A @ B^T + bias. B[j][k] pre-transposed bf16.
// Optional fp32 and/or bf16 outputs, optional relu.
// ---------------------------------------------------------------------------
__global__ __launch_bounds__(256)
void gemm_bf16_128(const ushort_t* __restrict__ A, const ushort_t* __restrict__ B,
                   const float* __restrict__ bias,
                   float* __restrict__ Cf, ushort_t* __restrict__ Cb, int relu) {
    const int wave = threadIdx.x >> 6, lane = threadIdx.x & 63;
    const int r0 = (blockIdx.x * 4 + wave) * 16;
    const int col = lane & 15, kg = lane >> 4;
    const int arow = min(r0 + col, NN - 1);
    short8 a[4];
#pragma unroll
    for (int ks = 0; ks < 4; ++ks)
        a[ks] = ld8(A + (size_t)arow * HH + ks * 32 + kg * 8);
    for (int j0 = 0; j0 < 8; ++j0) {
        float4v acc = {0,0,0,0};
        const ushort_t* bp = B + (size_t)(j0 * 16 + col) * HH + kg * 8;
#pragma unroll
        for (int ks = 0; ks < 4; ++ks)
            acc = __builtin_amdgcn_mfma_f32_16x16x32_bf16(a[ks], ld8(bp + ks * 32), acc, 0, 0, 0);
        const int j = j0 * 16 + col;
        const float bj = bias[j];
#pragma unroll
        for (int i = 0; i < 4; ++i) {
            const int node = r0 + kg * 4 + i;
            if (node >= NN) continue;
            float v = acc[i] + bj;
            if (relu) v = fmaxf(v, 0.f);
            const size_t off = (size_t)node * HH + j;
            if (Cf) Cf[off] = v;
            if (Cb) Cb[off] = f2b(v);
        }
    }
}

// ---------------------------------------------------------------------------
// fp32 GEMM kept for the tiny final [N,12] head.
// ---------------------------------------------------------------------------
__device__ __forceinline__ int swz_(int k) { return ((k >> 2) & 15) << 2; }

__global__ __launch_bounds__(256)
void gemm_abt(const float* __restrict__ A, const float* __restrict__ B,
              const float* __restrict__ bias, float* __restrict__ Cmat,
              int M, int Ngc, int act) {
    __shared__ float As[128 * 64];
    __shared__ float Bs[128 * 64];
    const int tid = threadIdx.x;
    const int bm = blockIdx.x << 6;
    const int bn = blockIdx.y << 6;

    for (int i = tid; i < 2048; i += 256) {
        const int r = i >> 5;
        const int c4 = (i & 31) << 2;
        const int s = swz_(c4);
        float4 v = make_float4(0.f, 0.f, 0.f, 0.f);
        const int gr = bm + r;
        if (gr < M) v = *(const float4*)(A + (size_t)gr * 128 + c4);
        As[(c4 + 0) * 64 + (r ^ s)] = v.x;
        As[(c4 + 1) * 64 + (r ^ s)] = v.y;
        As[(c4 + 2) * 64 + (r ^ s)] = v.z;
        As[(c4 + 3) * 64 + (r ^ s)] = v.w;
    }
    for (int i = tid; i < 2048; i += 256) {
        const int r = i >> 5;
        const int c4 = (i & 31) << 2;
        const int s = swz_(c4);
        float4 v = make_float4(0.f, 0.f, 0.f, 0.f);
        const int gr = bn + r;
        if (gr < Ngc) v = *(const float4*)(B + (size_t)gr * 128 + c4);
        Bs[(c4 + 0) * 64 + (r ^ s)] = v.x;
        Bs[(c4 + 1) * 64 + (r ^ s)] = v.y;
        Bs[(c4 + 2) * 64 + (r ^ s)] = v.z;
        Bs[(c4 + 3) * 64 + (r ^ s)] = v.w;
    }
    __syncthreads();

    const int tr = (tid >> 4) << 2;
    const int tc = (tid & 15) << 2;
    float acc[16] = {};
#pragma unroll 8
    for (int k = 0; k < 128; ++k) {
        const int s = swz_(k);
        const float4 a = *(const float4*)(&As[k * 64 + (tr ^ s)]);
        const float4 b = *(const float4*)(&Bs[k * 64 + (tc ^ s)]);
        acc[0]  += a.x * b.x; acc[1]  += a.x * b.y; acc[2]  += a.x * b.z; acc[3]  += a.x * b.w;
        acc[4]  += a.y * b.x; acc[5]  += a.y * b.y; acc[6]  += a.y * b.z; acc[7]  += a.y * b.w;
        acc[8]  += a.z * b.x; acc[9]  += a.z * b.y; acc[10] += a.z * b.z; acc[11] += a.z * b.w;
        acc[12] += a.w * b.x; acc[13] += a.w * b.y; acc[14] += a.w * b.z; acc[15] += a.w * b.w;
    }
#pragma unroll
    for (int i = 0; i < 4; ++i) {
        const int gr = bm + tr + i;
        if (gr >= M) continue;
#pragma unroll
        for (int j = 0; j < 4; ++j) {
            const int gc = bn + tc + j;
            if (gc >= Ngc) continue;
            float v = acc[i * 4 + j] + (bias ? bias[gc] : 0.f);
            if (act == 1) v = fmaxf(v, 0.f);
            Cmat[(size_t)gr * Ngc + gc] = v;
        }
    }
}

// ---------------------------------------------------------------------------
// CSR build (by dst).
// ---------------------------------------------------------------------------
__global__ void csr_count(const int* __restrict__ dst, int* __restrict__ cursor) {
    int e = blockIdx.x * 256 + threadIdx.x;
    if (e < EE) atomicAdd(&cursor[dst[e]], 1);
}

__global__ __launch_bounds__(1024)
void csr_scan(int* __restrict__ cursor, int* __restrict__ rowptr) {
    __shared__ int sm[1024];
    __shared__ int carry_s;
    if (threadIdx.x == 0) carry_s = 0;
    __syncthreads();
    for (int base = 0; base < NN; base += 1024) {
        int i = base + threadIdx.x;
        int v = (i < NN) ? cursor[i] : 0;
        int c = carry_s;
        __syncthreads();
        sm[threadIdx.x] = v;
        __syncthreads();
        for (int off = 1; off < 1024; off <<= 1) {
            int t = (threadIdx.x >= off) ? sm[threadIdx.x - off] : 0;
            __syncthreads();
            sm[threadIdx.x] += t;
            __syncthreads();
        }
        int excl = c + sm[threadIdx.x] - v;
        if (i < NN) { rowptr[i] = excl; cursor[i] = excl; }
        if (threadIdx.x == 0) carry_s = c + sm[1023];
        __syncthreads();
    }
    if (threadIdx.x == 0) rowptr[NN] = carry_s;
}

__global__ void csr_fill(const int* __restrict__ dst, int* __restrict__ cursor,
                         int* __restrict__ eidx) {
    int e = blockIdx.x * 256 + threadIdx.x;
    if (e >= EE) return;
    int pos = atomicAdd(&cursor[dst[e]], 1);
    eidx[pos] = e;
}

// ---------------------------------------------------------------------------
// GAT edge scores: one wave per edge, bf16 row reads, shfl reduce.
// ---------------------------------------------------------------------------
__global__ __launch_bounds__(256)
void gat_score(const int* __restrict__ src, const int* __restrict__ dst,
               const float* __restrict__ ea,
               const ushort_t* __restrict__ xlb, const ushort_t* __restrict__ xrb,
               const float* __restrict__ We, const float* __restrict__ att,
               float* __restrict__ sbuf) {
    int wid = (blockIdx.x * 256 + threadIdx.x) >> 6;   // edge id
    int lane = threadIdx.x & 63;
    if (wid >= EE) return;
    int sN = src[wid], dN = dst[wid];
    float eav = ea[wid];
    const ushort_t* pl = xlb + (size_t)sN * HH;
    const ushort_t* pr = xrb + (size_t)dN * HH;
    float mA = b2f(pl[lane]) + b2f(pr[lane]) + eav * We[lane];
    float mB = b2f(pl[lane + 64]) + b2f(pr[lane + 64]) + eav * We[lane + 64];
    mA = (mA > 0.f) ? mA : 0.2f * mA;
    mB = (mB > 0.f) ? mB : 0.2f * mB;
    float sA = mA * att[lane];
    float sB = mB * att[lane + 64];
#pragma unroll
    for (int off = 1; off < 32; off <<= 1) {
        sA += __shfl_xor(sA, off);
        sB += __shfl_xor(sB, off);
    }
    if ((lane & 31) == 0) {
        int h01 = lane >> 5;
        sbuf[(size_t)wid * 4 + h01]     = sA;
        sbuf[(size_t)wid * 4 + 2 + h01] = sB;
    }
}

// ---------------------------------------------------------------------------
// Per-dst-node aggregation + bias + LayerNorm + ELU + residual (fused).
// ---------------------------------------------------------------------------
__global__ __launch_bounds__(256)
void gat_aggregate(const int* __restrict__ rowptr, const int* __restrict__ eidx,
                   const int* __restrict__ src, const float* __restrict__ sbuf,
                   const float* __restrict__ xl,
                   const float* __restrict__ gbias, const float* __restrict__ gamma,
                   const float* __restrict__ beta,
                   float* __restrict__ h, ushort_t* __restrict__ hb) {
    int node = (blockIdx.x * 256 + threadIdx.x) >> 6;
    int lane = threadIdx.x & 63;
    if (node >= NN) return;
    int beg = rowptr[node], end = rowptr[node + 1];

    float m0 = -INFINITY, m1 = -INFINITY, m2 = -INFINITY, m3 = -INFINITY;
    for (int i = beg + lane; i < end; i += 64) {
        int eid = eidx[i];
        float4 s4 = *(const float4*)(sbuf + (size_t)eid * 4);
        m0 = fmaxf(m0, s4.x); m1 = fmaxf(m1, s4.y);
        m2 = fmaxf(m2, s4.z); m3 = fmaxf(m3, s4.w);
    }
#pragma unroll
    for (int off = 1; off < 64; off <<= 1) {
        m0 = fmaxf(m0, __shfl_xor(m0, off));
        m1 = fmaxf(m1, __shfl_xor(m1, off));
        m2 = fmaxf(m2, __shfl_xor(m2, off));
        m3 = fmaxf(m3, __shfl_xor(m3, off));
    }
    const int hA = lane >> 5;
    const float mxA = hA ? m1 : m0;
    const float mxB = hA ? m3 : m2;

    float accA = 0.f, accB = 0.f, denA = 0.f, denB = 0.f;
    for (int i = beg; i < end; ++i) {
        int eid = eidx[i];
        int sN = src[eid];
        float eA = expf(sbuf[(size_t)eid * 4 + hA] - mxA);
        float eB = expf(sbuf[(size_t)eid * 4 + 2 + hA] - mxB);
        const float* pl = xl + (size_t)sN * HH;
        accA += eA * pl[lane];
        accB += eB * pl[lane + 64];
        denA += eA; denB += eB;
    }
    float vA = accA / fmaxf(denA, 1e-16f) + gbias[lane];
    float vB = accB / fmaxf(denB, 1e-16f) + gbias[lane + 64];

    float sum = vA + vB;
    float ssq = vA * vA + vB * vB;
#pragma unroll
    for (int off = 1; off < 64; off <<= 1) {
        sum += __shfl_xor(sum, off);
        ssq += __shfl_xor(ssq, off);
    }
    float mean = sum * (1.f / 128.f);
    float var = ssq * (1.f / 128.f) - mean * mean;
    float inv = rsqrtf(var + 1e-5f);
    float yA = (vA - mean) * inv * gamma[lane] + beta[lane];
    float yB = (vB - mean) * inv * gamma[lane + 64] + beta[lane + 64];
    yA = (yA > 0.f) ? yA : expm1f(yA);
    yB = (yB > 0.f) ? yB : expm1f(yB);
    size_t offA = (size_t)node * HH + lane;
    size_t offB = offA + 64;
    float hnA = h[offA] + yA;
    float hnB = h[offB] + yB;
    h[offA] = hnA; h[offB] = hnB;
    hb[offA] = f2b(hnA); hb[offB] = f2b(hnB);
}

// ---------------------------------------------------------------------------
// Weight conversion kernels
// ---------------------------------------------------------------------------
__global__ void conv_bf16(const float* __restrict__ src, ushort_t* __restrict__ dst, int n) {
    int i = blockIdx.x * 256 + threadIdx.x;
    if (i < n) dst[i] = f2b(src[i]);
}

// fp32 [128,128] -> bf16 transposed [128,128]: dst[j*128+k] = src[k*128+j]
__global__ void convT_bf16(const float* __restrict__ src, ushort_t* __restrict__ dst) {
    int idx = blockIdx.x * 256 + threadIdx.x;
    if (idx >= 16384) return;
    int r = idx >> 7, c = idx & 127;
    dst[c * 128 + r] = f2b(src[r * 128 + c]);
}

__global__ void transpose_k(const float* __restrict__ src, float* __restrict__ dst,
                            int R, int Cc) {
    int idx = blockIdx.x * 256 + threadIdx.x;
    if (idx >= R * Cc) return;
    int r = idx / Cc, c = idx % Cc;
    dst[(size_t)c * R + r] = src[(size_t)r * Cc + c];
}

// ---------------------------------------------------------------------------
extern "C" void kernel_launch(void* const* d_in, const int* in_sizes, int n_in,
                              void* d_out, int out_size, void* d_ws, size_t ws_size,
                              hipStream_t stream) {
    const float* x     = (const float*)d_in[0];
    const int*   ei    = (const int*)d_in[1];
    const int*   src   = ei;
    const int*   dst   = ei + EE;
    const float* ea    = (const float*)d_in[2];
    const float* Wih0  = (const float*)d_in[3];
    const float* Whh0  = (const float*)d_in[4];
    const float* bih0  = (const float*)d_in[5];
    const float* bhh0  = (const float*)d_in[6];
    const float* Wih1  = (const float*)d_in[7];
    const float* Whh1  = (const float*)d_in[8];
    const float* bih1  = (const float*)d_in[9];
    const float* bhh1  = (const float*)d_in[10];
    const float* gWl   = (const float*)d_in[11];
    const float* gbl   = (const float*)d_in[12];
    const float* gWr   = (const float*)d_in[13];
    const float* gbr   = (const float*)d_in[14];
    const float* gWe   = (const float*)d_in[15];
    const float* gatt  = (const float*)d_in[16];
    const float* gbias = (const float*)d_in[17];
    const float* lng   = (const float*)d_in[18];
    const float* lnb   = (const float*)d_in[19];
    const float* fcW1  = (const float*)d_in[20];
    const float* fcb1  = (const float*)d_in[21];
    const float* fcW2  = (const float*)d_in[22];
    const float* fcb2  = (const float*)d_in[23];
    float* out = (float*)d_out;
    float* ws  = (float*)d_ws;

    const size_t NH = (size_t)NN * HH;        // 6.4M elems

    // ushort region first (16B-aligned sub-buffers)
    ushort_t* h0b   = (ushort_t*)ws;          // NH
    ushort_t* h1b   = h0b + NH;               // NH
    ushort_t* xlb   = h1b + NH;               // NH
    ushort_t* xrb   = xlb + NH;               // NH
    ushort_t* Whh0b = xrb + NH;               // 384*128
    ushort_t* Wih1b = Whh0b + 49152;
    ushort_t* Whh1b = Wih1b + 49152;
    ushort_t* WlTb  = Whh1b + 49152;          // 3*16384
    ushort_t* WrTb  = WlTb + 49152;           // 3*16384
    ushort_t* W1Tb  = WrTb + 49152;           // 16384
    // total ushorts = 4*NH + 5*49152 + 16384 = 25,862,144 (even)

    float* p    = ws + (4 * NH + 5 * 49152 + 16384) / 2;
    float* h0f  = p; p += NH;
    float* h1f  = p; p += NH;
    float* hfc  = p; p += NH;
    float* xl   = p; p += NH;
    float* sbuf = p; p += (size_t)EE * 4;
    float* W2T  = p; p += 2048;
    int* rowptr = (int*)p;
    int* cursor = rowptr + (NN + 1);
    int* eidx   = cursor + NN;

    // --- weight conversions ---
    conv_bf16<<<192, 256, 0, stream>>>(Whh0, Whh0b, 49152);
    conv_bf16<<<192, 256, 0, stream>>>(Wih1, Wih1b, 49152);
    conv_bf16<<<192, 256, 0, stream>>>(Whh1, Whh1b, 49152);
    for (int l = 0; l < LLAYERS; ++l) {
        convT_bf16<<<64, 256, 0, stream>>>(gWl + (size_t)l * 16384, WlTb + (size_t)l * 16384);
        convT_bf16<<<64, 256, 0, stream>>>(gWr + (size_t)l * 16384, WrTb + (size_t)l * 16384);
    }
    convT_bf16<<<64, 256, 0, stream>>>(fcW1, W1Tb);
    transpose_k<<<6, 256, 0, stream>>>(fcW2, W2T, 128, 12);

    // --- GRU ---
    hipMemsetAsync(h0b, 0, NH * sizeof(ushort_t), stream);
    hipMemsetAsync(h1b, 0, NH * sizeof(ushort_t), stream);
    hipMemsetAsync(h0f, 0, NH * sizeof(float), stream);
    hipMemsetAsync(h1f, 0, NH * sizeof(float), stream);

    const int gruBlocks = (NN + 63) / 64;   // 782
    for (int t = 0; t < TT; ++t) {
        gru_step0<<<gruBlocks, 256, 0, stream>>>(x, t, h0b, h0f, Whh0b, Wih0, bih0, bhh0);
        gru_step1<<<gruBlocks, 256, 0, stream>>>(h0b, h1b, h1f, Wih1b, Whh1b, bih1, bhh1);
    }

    // --- CSR by dst (topology shared by all 3 GAT layers) ---
    hipMemsetAsync(cursor, 0, NN * sizeof(int), stream);
    csr_count<<<(EE + 255) / 256, 256, 0, stream>>>(dst, cursor);
    csr_scan<<<1, 1024, 0, stream>>>(cursor, rowptr);
    csr_fill<<<(EE + 255) / 256, 256, 0, stream>>>(dst, cursor, eidx);

    // --- GAT layers ---
    const int scoreBlocks = (EE * 64 + 255) / 256;
    const int aggBlocks = (NN * 64 + 255) / 256;
    for (int l = 0; l < LLAYERS; ++l) {
        gemm_bf16_128<<<gruBlocks, 256, 0, stream>>>(h1b, WlTb + (size_t)l * 16384,
                                                     gbl + l * HH, xl, xlb, 0);
        gemm_bf16_128<<<gruBlocks, 256, 0, stream>>>(h1b, WrTb + (size_t)l * 16384,
                                                     gbr + l * HH, nullptr, xrb, 0);
        gat_score<<<scoreBlocks, 256, 0, stream>>>(src, dst, ea, xlb, xrb,
                                                   gWe + l * HH, gatt + l * HH, sbuf);
        gat_aggregate<<<aggBlocks, 256, 0, stream>>>(rowptr, eidx, src, sbuf, xl,
                                                     gbias + l * HH, lng + l * HH, lnb + l * HH,
                                                     h1f, h1b);
    }

    // --- FC head ---
    gemm_bf16_128<<<gruBlocks, 256, 0, stream>>>(h1b, W1Tb, fcb1, hfc, nullptr, 1);
    dim3 g12((NN + 63) / 64, 1);
    gemm_abt<<<g12, 256, 0, stream>>>(hfc, W2T, fcb2, out, NN, OO, 0);
}